// Round 7
// baseline (212.315 us; speedup 1.0000x reference)
//
#include <hip/hip_runtime.h>
#include <stdint.h>

// ---------------------------------------------------------------------------
// MultiHeadAttention_19224273617233  (B=1, S1=S2=2048, D=1024, H=16, D_K=64,
// RADIUS=64, SEGMENTED, dense softmax over all 2048 keys)
//
// R7 pipeline (all bf16 MFMA internally; f32 in/out; tol = 2% of absmax):
//   0. convert : K,V,Wk,Wv,Wc -> bf16; rel -> relb[16][144][64] bf16 zero-pad
//   0b seg_prep: per-row segment interval [lo,hi] (segments are contiguous)
//   1. qp      : Qp[h][i][d] = Q[i][d*16+h] * (log2e/8)  (bf16)
//   2. qe_gemm : qe[h][i][l] = Qp[h][i][:]·relb[h][l][:]  (MFMA, l padded 144)
//   3. proj    : fused GEMM (BK=64, dbuf): Kp[h][j][d], Vp[h][d][j]
//   4. attn    : j-range split in thirds (grid 32x16x3 -> 3 blocks/CU);
//                no-max softmax (exp2), row-sum via all-ones MFMA; blocks
//                emit unnormalized O/l partials (no max => partials just add)
//   5. merge   : heads = (sum_jh O_jh) / (sum_jh l_jh)  (bf16)
//   6. outproj : out = heads @ Wc^T (f32), 128x64 dbuf (R5-verified)
// ---------------------------------------------------------------------------

typedef __attribute__((ext_vector_type(4))) float f32x4;
typedef __attribute__((ext_vector_type(8))) short s16x8;
typedef __attribute__((ext_vector_type(4))) unsigned short u16x4;
typedef __attribute__((ext_vector_type(2))) unsigned short u16x2;

#define MFMA16(a, b, c) __builtin_amdgcn_mfma_f32_16x16x32_bf16((a), (b), (c), 0, 0, 0)

// Q pre-scale: 1/sqrt(D_K)=1/8 folded with log2(e) so softmax uses raw v_exp_f32
#define QSCALE 0.1803368801111204f

__device__ __forceinline__ unsigned short f2bf(float f) {
  unsigned int u = __builtin_bit_cast(unsigned int, f);
  u += 0x7fffu + ((u >> 16) & 1u);  // round-to-nearest-even
  return (unsigned short)(u >> 16);
}
__device__ __forceinline__ float bf2f(unsigned short b) {
  unsigned int u = ((unsigned int)b) << 16;
  return __builtin_bit_cast(float, u);
}

// async 16B/lane global->LDS DMA; LDS dest is wave-uniform base + lane*16
__device__ __forceinline__ void async_copy16(const void* g, void* l) {
  __builtin_amdgcn_global_load_lds(
      (const __attribute__((address_space(1))) unsigned int*)g,
      (__attribute__((address_space(3))) unsigned int*)l, 16, 0, 0);
}

// ---------------------------------------------------------------------------
// convert: 5 f32 arrays -> bf16, plus relb (zero-padded l: 130 -> 144).
// ---------------------------------------------------------------------------
__global__ __launch_bounds__(256) void convert_kernel(
    const float* __restrict__ K, const float* __restrict__ V,
    const float* __restrict__ Wk, const float* __restrict__ Wv,
    const float* __restrict__ Wc, const float* __restrict__ rel,
    unsigned short* __restrict__ Kb, unsigned short* __restrict__ Vb,
    unsigned short* __restrict__ Wkb, unsigned short* __restrict__ Wvb,
    unsigned short* __restrict__ Wcb, unsigned short* __restrict__ relb) {
  size_t v = (size_t)blockIdx.x * 256 + threadIdx.x;  // vec4 index
  const size_t M4 = 1u << 18;                         // 1M elems in vec4 units
  if (v >= 7 * M4) {
    size_t rv = v - 7 * M4;  // relb: 16*144*16 = 36864 vec4 chunks
    if (rv >= 36864) return;
    int hh = (int)(rv / (144 * 16));
    int rem = (int)(rv % (144 * 16));
    int l = rem >> 4, dch = rem & 15;
    u16x4 p = {0, 0, 0, 0};
    if (l < 130) {
      f32x4 x = ((const f32x4*)rel)[((size_t)hh * 130 + l) * 16 + dch];
      p = (u16x4){f2bf(x[0]), f2bf(x[1]), f2bf(x[2]), f2bf(x[3])};
    }
    ((u16x4*)relb)[rv] = p;
    return;
  }
  const float* src;
  unsigned short* dst;
  size_t off;
  if (v < 2 * M4) { src = K; dst = Kb; off = v; }
  else if (v < 4 * M4) { src = V; dst = Vb; off = v - 2 * M4; }
  else if (v < 5 * M4) { src = Wk; dst = Wkb; off = v - 4 * M4; }
  else if (v < 6 * M4) { src = Wv; dst = Wvb; off = v - 5 * M4; }
  else { src = Wc; dst = Wcb; off = v - 6 * M4; }
  f32x4 x = ((const f32x4*)src)[off];
  u16x4 p = {f2bf(x[0]), f2bf(x[1]), f2bf(x[2]), f2bf(x[3])};
  ((u16x4*)dst)[off] = p;
}

// ---------------------------------------------------------------------------
// seg_prep: lo[i]/hi[i] = first/last index with seg==seg[i] (sorted segments).
// ---------------------------------------------------------------------------
__global__ __launch_bounds__(256) void seg_prep_kernel(const int* __restrict__ seg,
                                                       int* __restrict__ lo,
                                                       int* __restrict__ hi) {
  const int i = blockIdx.x * 256 + threadIdx.x;  // 2048
  const bool is64 = (seg[2047] == 0);  // int64 storage: [2047] is a high word
  auto rd = [&](int k) { return is64 ? seg[2 * k] : seg[k]; };
  const int s = rd(i);
  int a = 0, b = i;
  while (a < b) { int m = (a + b) >> 1; if (rd(m) < s) a = m + 1; else b = m; }
  lo[i] = a;
  int c = i, d = 2048;
  while (c < d) { int m = (c + d) >> 1; if (rd(m) <= s) c = m + 1; else d = m; }
  hi[i] = c - 1;
}

// ---------------------------------------------------------------------------
// qp: Qp[h][i][d] = Q[i][d*16+h] * QSCALE  (bf16)   (16 query rows per block)
// ---------------------------------------------------------------------------
__global__ __launch_bounds__(256, 2) void qp_kernel(const float* __restrict__ Q,
                                                    unsigned short* __restrict__ Qp) {
  __shared__ __align__(16) unsigned short QL[16][1032];
  const int tid = threadIdx.x;
  const int i0 = blockIdx.x * 16;

#pragma unroll
  for (int ii = 0; ii < 16; ++ii) {
    int lin = tid + 256 * ii;
    int row = lin >> 8, ch = lin & 255;
    f32x4 v = *(const f32x4*)(Q + (size_t)(i0 + row) * 1024 + ch * 4);
    u16x4 pk = {f2bf(v[0]), f2bf(v[1]), f2bf(v[2]), f2bf(v[3])};
    *(u16x4*)&QL[row][ch * 4] = pk;
  }
  __syncthreads();

  const int i = tid & 15, hh = tid >> 4;
#pragma unroll
  for (int d4 = 0; d4 < 16; ++d4) {
    u16x4 pk;
#pragma unroll
    for (int e = 0; e < 4; ++e)
      pk[e] = f2bf(bf2f(QL[i][(d4 * 4 + e) * 16 + hh]) * QSCALE);
    *(u16x4*)(Qp + ((size_t)hh * 2048 + i0 + i) * 64 + d4 * 4) = pk;
  }
}

// ---------------------------------------------------------------------------
// qe_gemm: per head, qe[h][i0..i0+128][l=0..144) = Qp-tile @ relb[h]^T.
// (Qp is QSCALE-scaled, so qe inherits the log2e/8 factor.)
// ---------------------------------------------------------------------------
__global__ __launch_bounds__(256, 2) void qe_gemm_kernel(
    const unsigned short* __restrict__ Qp, const unsigned short* __restrict__ relb,
    unsigned short* __restrict__ qe) {
  __shared__ __align__(16) unsigned short As[128 * 64];  // swizzled: chunk^(r&7)
  __shared__ __align__(16) unsigned short Bs[144][72];   // padded rows

  const int tid = threadIdx.x;
  const int lane = tid & 63, w = tid >> 6;
  const int col = lane & 15, quad = lane >> 4;
  const int h = blockIdx.y;
  const int i0 = blockIdx.x * 128;
  const int lr = lane >> 3, lc = lane & 7;

#pragma unroll
  for (int t = 0; t < 4; ++t) {
    int r = (w + t * 4) * 8 + lr;
    async_copy16(Qp + ((size_t)(h * 2048 + i0 + r)) * 64 + (size_t)(lc ^ (r & 7)) * 8,
                 As + (w + t * 4) * 512);
  }
  for (int c = tid; c < 1152; c += 256) {
    int row = c >> 3, ch = c & 7;
    *(f32x4*)&Bs[row][ch * 8] =
        *(const f32x4*)(relb + ((size_t)(h * 144 + row)) * 64 + ch * 8);
  }
  __syncthreads();

  s16x8 af[2][2];
#pragma unroll
  for (int ms = 0; ms < 2; ++ms) {
    int r = w * 32 + ms * 16 + col;
#pragma unroll
    for (int kk = 0; kk < 2; ++kk)
      af[ms][kk] = *(const s16x8*)&As[r * 64 + ((kk * 4 + quad) ^ (r & 7)) * 8];
  }

  f32x4 acc[2][9];
#pragma unroll
  for (int ms = 0; ms < 2; ++ms)
#pragma unroll
    for (int ns = 0; ns < 9; ++ns) acc[ms][ns] = (f32x4){0.f, 0.f, 0.f, 0.f};

#pragma unroll
  for (int ns = 0; ns < 9; ++ns) {
    s16x8 b0 = *(const s16x8*)&Bs[ns * 16 + col][quad * 8];
    s16x8 b1 = *(const s16x8*)&Bs[ns * 16 + col][32 + quad * 8];
#pragma unroll
    for (int ms = 0; ms < 2; ++ms) {
      acc[ms][ns] = MFMA16(af[ms][0], b0, acc[ms][ns]);
      acc[ms][ns] = MFMA16(af[ms][1], b1, acc[ms][ns]);
    }
  }

#pragma unroll
  for (int ms = 0; ms < 2; ++ms)
#pragma unroll
    for (int ns = 0; ns < 9; ++ns)
#pragma unroll
      for (int r = 0; r < 4; ++r) {
        int m = i0 + w * 32 + ms * 16 + quad * 4 + r;
        qe[((size_t)h * 2048 + m) * 144 + ns * 16 + col] = f2bf(acc[ms][ns][r]);
      }
}

// ---------------------------------------------------------------------------
// GEMM core: 128x64 tile, BK=64, double-buffered async staging.
// ---------------------------------------------------------------------------
__device__ __forceinline__ void gemm_core_128x64_db(
    const unsigned short* __restrict__ A, const unsigned short* __restrict__ B,
    int bm, int bn, int K, unsigned short* As, unsigned short* Bs,
    f32x4 (&acc)[4][2]) {
  const int tid = threadIdx.x;
  const int lane = tid & 63, w = tid >> 6;
  const int col = lane & 15, quad = lane >> 4;
  const int wm = (w >> 1) * 64, wn = (w & 1) * 32;
  const int lr = lane >> 3, lc = lane & 7;  // 8 rows x 8 chunks per issue

  auto stage = [&](int buf, int kt) {
#pragma unroll
    for (int t = 0; t < 4; ++t) {  // A: 128 rows
      int r = (w + t * 4) * 8 + lr;
      async_copy16(A + (size_t)(bm + r) * K + kt * 64 + (size_t)(lc ^ (r & 7)) * 8,
                   As + buf * 8192 + (w + t * 4) * 512);
    }
#pragma unroll
    for (int t = 0; t < 2; ++t) {  // B: 64 rows
      int r = (w + t * 4) * 8 + lr;
      async_copy16(B + (size_t)(bn + r) * K + kt * 64 + (size_t)(lc ^ (r & 7)) * 8,
                   Bs + buf * 4096 + (w + t * 4) * 512);
    }
  };

  const int nk = K >> 6;
  stage(0, 0);
  for (int kt = 0; kt < nk; ++kt) {
    __syncthreads();
    if (kt + 1 < nk) stage((kt + 1) & 1, kt + 1);
    const unsigned short* Ab = As + (kt & 1) * 8192;
    const unsigned short* Bb = Bs + (kt & 1) * 4096;

    s16x8 af[4][2], bfr[2][2];
#pragma unroll
    for (int ms = 0; ms < 4; ++ms) {
      int r = wm + ms * 16 + col;
#pragma unroll
      for (int kk = 0; kk < 2; ++kk)
        af[ms][kk] = *(const s16x8*)&Ab[r * 64 + ((kk * 4 + quad) ^ (r & 7)) * 8];
    }
#pragma unroll
    for (int ns = 0; ns < 2; ++ns) {
      int r = wn + ns * 16 + col;
#pragma unroll
      for (int kk = 0; kk < 2; ++kk)
        bfr[ns][kk] = *(const s16x8*)&Bb[r * 64 + ((kk * 4 + quad) ^ (r & 7)) * 8];
    }
#pragma unroll
    for (int kk = 0; kk < 2; ++kk)
#pragma unroll
      for (int ms = 0; ms < 4; ++ms)
#pragma unroll
        for (int ns = 0; ns < 2; ++ns)
          acc[ms][ns] = MFMA16(af[ms][kk], bfr[ns][kk], acc[ms][ns]);
  }
}

// ---------------------------------------------------------------------------
// proj: blocks [0,256) -> Kp[h][j][d] = K@Wk^T;  [256,512) -> Vp[h][d][j].
// ---------------------------------------------------------------------------
__global__ __launch_bounds__(256, 2) void proj_kernel(
    const unsigned short* __restrict__ Kb, const unsigned short* __restrict__ Wkb,
    const unsigned short* __restrict__ Wvb, const unsigned short* __restrict__ Vb,
    unsigned short* __restrict__ Kp, unsigned short* __restrict__ Vp) {
  __shared__ __align__(16) unsigned short As[2 * 128 * 64];
  __shared__ __align__(16) unsigned short Bs[2 * 64 * 64];

  const int bx = blockIdx.x;
  const bool modeK = bx < 256;
  const unsigned short *A, *B;
  int bm, bn;
  if (modeK) {
    A = Kb; B = Wkb;
    bm = (bx >> 4) * 128; bn = (bx & 15) * 64;
  } else {
    int b = bx - 256;
    A = Wvb; B = Vb;
    bm = (b >> 5) * 128; bn = (b & 31) * 64;
  }

  f32x4 acc[4][2];
#pragma unroll
  for (int a = 0; a < 4; ++a)
#pragma unroll
    for (int b2 = 0; b2 < 2; ++b2) acc[a][b2] = (f32x4){0.f, 0.f, 0.f, 0.f};

  gemm_core_128x64_db(A, B, bm, bn, 1024, As, Bs, acc);

  const int lane = threadIdx.x & 63, w = threadIdx.x >> 6;
  const int col = lane & 15, quad = lane >> 4;
  const int wm = (w >> 1) * 64, wn = (w & 1) * 32;

  if (modeK) {
    const int dbase = (bn + wn) >> 4;
#pragma unroll
    for (int ms = 0; ms < 4; ++ms)
#pragma unroll
      for (int r = 0; r < 4; ++r) {
        int m = bm + wm + ms * 16 + quad * 4 + r;
        u16x2 pk = {f2bf(acc[ms][0][r]), f2bf(acc[ms][1][r])};
        *(u16x2*)(Kp + ((size_t)col * 2048 + m) * 64 + dbase) = pk;
      }
  } else {
#pragma unroll
    for (int ms = 0; ms < 4; ++ms)
#pragma unroll
      for (int r = 0; r < 4; ++r) {
        int m = bm + wm + ms * 16 + quad * 4 + r;
        int hh = m & 15, dd = m >> 4;
#pragma unroll
        for (int ns = 0; ns < 2; ++ns) {
          int j = bn + wn + ns * 16 + col;
          Vp[((size_t)hh * 64 + dd) * 2048 + j] = f2bf(acc[ms][ns][r]);
        }
      }
  }
}

// ---------------------------------------------------------------------------
// outproj: out[i][n] = sum_o heads[i][o] * Wc[n][o]   (f32 out)  [R5-verified]
// ---------------------------------------------------------------------------
__global__ __launch_bounds__(256, 2) void outproj_kernel(
    const unsigned short* __restrict__ Hb, const unsigned short* __restrict__ Wcb,
    float* __restrict__ out) {
  __shared__ __align__(16) unsigned short As[2 * 128 * 64];
  __shared__ __align__(16) unsigned short Bs[2 * 64 * 64];

  const int bx = blockIdx.x;
  const int bm = (bx >> 4) * 128, bn = (bx & 15) * 64;

  f32x4 acc[4][2];
#pragma unroll
  for (int a = 0; a < 4; ++a)
#pragma unroll
    for (int b2 = 0; b2 < 2; ++b2) acc[a][b2] = (f32x4){0.f, 0.f, 0.f, 0.f};

  gemm_core_128x64_db(Hb, Wcb, bm, bn, 1024, As, Bs, acc);

  const int lane = threadIdx.x & 63, w = threadIdx.x >> 6;
  const int col = lane & 15, quad = lane >> 4;
  const int wm = (w >> 1) * 64, wn = (w & 1) * 32;
#pragma unroll
  for (int ms = 0; ms < 4; ++ms)
#pragma unroll
    for (int ns = 0; ns < 2; ++ns)
#pragma unroll
      for (int r = 0; r < 4; ++r) {
        int m = bm + wm + ms * 16 + quad * 4 + r;
        int n = bn + wn + ns * 16 + col;
        out[(size_t)m * 1024 + n] = acc[ms][ns][r];
      }
}

// ---------------------------------------------------------------------------
// attn: grid (32 i-tiles, 16 heads, 3 j-thirds), 4 waves, wave = 16 q-rows.
// Inner loop byte-identical to the R5-verified kernel (single-buffered K/V
// staging, exp2 softmax, all-ones row-sum MFMA, Pst LDS transpose).  Each
// block covers j-tiles [jh*11, +11|10) and emits unnormalized partials:
//   Opart[jh][h][i][d] (bf16), Lpart[jh][h][i] (f32).
// No-max softmax => partials combine by plain addition in merge_kernel.
// LDS 44.5 KB -> 3 blocks/CU; grid 1536 = 2 x 768 (zero tail).
// ---------------------------------------------------------------------------
__global__ __launch_bounds__(256, 3) void attn_kernel(
    const unsigned short* __restrict__ Qp, const unsigned short* __restrict__ Kp,
    const unsigned short* __restrict__ Vp, const unsigned short* __restrict__ qe,
    const int* __restrict__ lo, const int* __restrict__ hi,
    unsigned short* __restrict__ Opart, float* __restrict__ Lpart) {
  __shared__ __align__(16) unsigned short Kt[64 * 64];  // [j][d], swizzled
  __shared__ __align__(16) unsigned short Vt[64 * 64];  // [d][j], swizzled
  __shared__ __align__(16) unsigned short QE[64][144];  // [i_local][l]
  __shared__ __align__(16) unsigned short Pst[4][16][72];
  __shared__ int loL[64], hiL[64];

  const int tid = threadIdx.x;
  const int lane = tid & 63;
  const int w = tid >> 6;
  const int col = lane & 15;
  const int quad = lane >> 4;
  const int h = blockIdx.y;
  const int bi = blockIdx.x;
  const int i0 = bi * 64;
  const int jh = blockIdx.z;                 // j-third
  const int jt_beg = jh * 11;
  const int jt_cnt = (jh < 2) ? 11 : 10;     // 11+11+10 = 32 tiles
  const int lr = lane >> 3, lc = lane & 7;

  if (tid < 64) { loL[tid] = lo[i0 + tid]; hiL[tid] = hi[i0 + tid]; }
#pragma unroll
  for (int ii = 0; ii < 5; ++ii) {
    int lin = tid + 256 * ii;  // 64 rows x 18 chunks = 1152
    if (lin < 1152) {
      int row = lin / 18, ch = lin % 18;
      *(f32x4*)&QE[row][ch * 8] =
          *(const f32x4*)(qe + ((size_t)(h * 2048 + i0 + row)) * 144 + ch * 8);
    }
  }
  __syncthreads();

  // per-row (4 rows per lane) constants
  int il[4], lo_r[4];
  unsigned span[4];
  float c0[4], c128[4], c129[4];
#pragma unroll
  for (int r = 0; r < 4; ++r) {
    il[r] = w * 16 + quad * 4 + r;
    lo_r[r] = loL[il[r]];
    span[r] = (unsigned)(hiL[il[r]] - lo_r[r]);
    c0[r] = bf2f(QE[il[r]][0]);
    c128[r] = bf2f(QE[il[r]][128]);
    c129[r] = bf2f(QE[il[r]][129]);
  }

  const int iw = i0 + w * 16;
  s16x8 aq0 = *(const s16x8*)(Qp + ((size_t)(h * 2048 + iw + col)) * 64 + quad * 8);
  s16x8 aq1 = *(const s16x8*)(Qp + ((size_t)(h * 2048 + iw + col)) * 64 + 32 + quad * 8);

  s16x8 ones;
#pragma unroll
  for (int e = 0; e < 8; ++e) ones[e] = (short)0x3F80;  // bf16 1.0

  f32x4 o[4], o4;
#pragma unroll
  for (int t = 0; t < 4; ++t) o[t] = (f32x4){0.f, 0.f, 0.f, 0.f};
  o4 = (f32x4){0.f, 0.f, 0.f, 0.f};

  for (int jtl = 0; jtl < jt_cnt; ++jtl) {
    const int jt = jt_beg + jtl;
    const int j0 = jt * 64;
    __syncthreads();  // previous tile fully consumed
    {
      int r = w * 8 + lr, r2 = (w + 4) * 8 + lr;
      async_copy16(Kp + ((size_t)(h * 2048 + j0 + r)) * 64 + (size_t)(lc ^ (r & 7)) * 8,
                   Kt + w * 512);
      async_copy16(Kp + ((size_t)(h * 2048 + j0 + r2)) * 64 + (size_t)(lc ^ (r2 & 7)) * 8,
                   Kt + (w + 4) * 512);
      async_copy16(Vp + ((size_t)(h * 64 + r)) * 2048 + j0 + (size_t)(lc ^ (r & 7)) * 8,
                   Vt + w * 512);
      async_copy16(Vp + ((size_t)(h * 64 + r2)) * 2048 + j0 + (size_t)(lc ^ (r2 & 7)) * 8,
                   Vt + (w + 4) * 512);
    }
    __syncthreads();  // DMA drained

    // S = (Q*QSCALE) K^T  (16 x 64 per wave), log2-domain
    f32x4 s[4];
#pragma unroll
    for (int ns = 0; ns < 4; ++ns) {
      int r = ns * 16 + col, sw = r & 7;
      s16x8 bk0 = *(const s16x8*)&Kt[r * 64 + (quad ^ sw) * 8];
      s16x8 bk1 = *(const s16x8*)&Kt[r * 64 + ((quad + 4) ^ sw) * 8];
      f32x4 z = (f32x4){0.f, 0.f, 0.f, 0.f};
      z = MFMA16(aq0, bk0, z);
      z = MFMA16(aq1, bk1, z);
      s[ns] = z;
    }

    // + bias (qe carries the same QSCALE factor), then P = exp2(s)
    const int dt = jt - bi;
    if (dt < -1 || dt > 1) {
      const bool right = dt > 1;  // wave-uniform
#pragma unroll
      for (int ns = 0; ns < 4; ++ns) {
        int j = j0 + ns * 16 + col;
#pragma unroll
        for (int r = 0; r < 4; ++r) {
          float cin = right ? c128[r] : c0[r];
          bool same = (unsigned)(j - lo_r[r]) <= span[r];
          s[ns][r] += same ? cin : c129[r];
        }
      }
    } else {
#pragma unroll
      for (int ns = 0; ns < 4; ++ns) {
        int j = j0 + ns * 16 + col;
#pragma unroll
        for (int r = 0; r < 4; ++r) {
          int rel = j - (i0 + il[r]);
          int rc = rel < -64 ? -64 : (rel > 64 ? 64 : rel);
          bool same = (unsigned)(j - lo_r[r]) <= span[r];
          int idx = same ? (rc + 64) : 129;
          s[ns][r] += bf2f(QE[il[r]][idx]);
        }
      }
    }
#pragma unroll
    for (int ns = 0; ns < 4; ++ns)
#pragma unroll
      for (int r = 0; r < 4; ++r)
        s[ns][r] = __builtin_amdgcn_exp2f(fminf(s[ns][r], 60.f));

    // P: C-layout -> A-layout via per-wave LDS region (wave-private)
#pragma unroll
    for (int ns = 0; ns < 4; ++ns)
#pragma unroll
      for (int r = 0; r < 4; ++r)
        Pst[w][quad * 4 + r][ns * 16 + col] = f2bf(s[ns][r]);

    s16x8 ap0 = *(const s16x8*)&Pst[w][col][quad * 8];
    s16x8 ap1 = *(const s16x8*)&Pst[w][col][32 + quad * 8];
#pragma unroll
    for (int t = 0; t < 4; ++t) {
      int r = t * 16 + col, sw = r & 7;
      s16x8 bv0 = *(const s16x8*)&Vt[r * 64 + (quad ^ sw) * 8];
      s16x8 bv1 = *(const s16x8*)&Vt[r * 64 + ((quad + 4) ^ sw) * 8];
      o[t] = MFMA16(ap0, bv0, o[t]);
      o[t] = MFMA16(ap1, bv1, o[t]);
    }
    o4 = MFMA16(ap0, ones, o4);  // row sums: every column gets sum_j P[i][j]
    o4 = MFMA16(ap1, ones, o4);
  }

  // emit unnormalized partials
#pragma unroll
  for (int t = 0; t < 4; ++t)
#pragma unroll
    for (int r = 0; r < 4; ++r) {
      int i = i0 + w * 16 + quad * 4 + r;
      int d = t * 16 + col;
      Opart[(((size_t)jh * 16 + h) * 2048 + i) * 64 + d] = f2bf(o[t][r]);
    }
  if (col == 0) {
#pragma unroll
    for (int r = 0; r < 4; ++r) {
      int i = i0 + w * 16 + quad * 4 + r;
      Lpart[((size_t)jh * 16 + h) * 2048 + i] = o4[r];
    }
  }
}

// ---------------------------------------------------------------------------
// merge: heads[i][d*16+h] = (sum_jh Opart) / (sum_jh Lpart)
// thread = (h, i, d4); 524288 threads.
// ---------------------------------------------------------------------------
__global__ __launch_bounds__(256) void merge_kernel(
    const unsigned short* __restrict__ Opart, const float* __restrict__ Lpart,
    unsigned short* __restrict__ heads) {
  const int idx = blockIdx.x * 256 + threadIdx.x;
  const int d4 = idx & 15;
  const int i = (idx >> 4) & 2047;
  const int h = idx >> 15;

  float o0 = 0.f, o1 = 0.f, o2 = 0.f, o3 = 0.f, l = 0.f;
#pragma unroll
  for (int jh = 0; jh < 3; ++jh) {
    size_t base = (((size_t)jh * 16 + h) * 2048 + i) * 64 + d4 * 4;
    u16x4 p = *(const u16x4*)(Opart + base);
    o0 += bf2f(p[0]); o1 += bf2f(p[1]); o2 += bf2f(p[2]); o3 += bf2f(p[3]);
    l += Lpart[((size_t)jh * 16 + h) * 2048 + i];
  }
  const float inv = 1.f / l;
  unsigned short* dst = heads + (size_t)i * 1024 + (size_t)d4 * 64 + h;
  dst[0] = f2bf(o0 * inv);
  dst[16] = f2bf(o1 * inv);
  dst[32] = f2bf(o2 * inv);
  dst[48] = f2bf(o3 * inv);
}

// ---------------------------------------------------------------------------
extern "C" void kernel_launch(void* const* d_in, const int* in_sizes, int n_in,
                              void* d_out, int out_size, void* d_ws, size_t ws_size,
                              hipStream_t stream) {
  const float* Q = (const float*)d_in[0];
  const float* K = (const float*)d_in[1];
  const float* V = (const float*)d_in[2];
  const int* seg = (const int*)d_in[3];
  // d_in[4] = padding_mask: all-false, unused (HARD_MASKING=False)
  const float* Wk = (const float*)d_in[5];
  const float* Wv = (const float*)d_in[6];
  const float* Wc = (const float*)d_in[7];
  const float* rel = (const float*)d_in[8];
  float* out = (float*)d_out;

  char* ws = (char*)d_ws;
  unsigned short* Kp = (unsigned short*)(ws);                    // [16][2048][64] 4 MB
  unsigned short* Vp = (unsigned short*)(ws + (4ull << 20));     // [16][64][2048] 4 MB
  unsigned short* Qp = (unsigned short*)(ws + (8ull << 20));     // [16][2048][64] 4 MB
  unsigned short* heads = (unsigned short*)(ws + (12ull << 20)); // [2048][1024] 4 MB
  unsigned short* qe = (unsigned short*)(ws + (16ull << 20));    // [16][2048][144] 9.4 MB
  unsigned short* Kb = (unsigned short*)(ws + (26ull << 20));    // 4 MB (dead after proj)
  unsigned short* Vb = (unsigned short*)(ws + (30ull << 20));    // 4 MB (dead after proj)
  unsigned short* Wkb = (unsigned short*)(ws + (34ull << 20));   // 2 MB (dead after proj)
  unsigned short* Wvb = (unsigned short*)(ws + (36ull << 20));   // 2 MB (dead after proj)
  unsigned short* Wcb = (unsigned short*)(ws + (38ull << 20));   // 2 MB
  unsigned short* relb = (unsigned short*)(ws + (40ull << 20));  // 288 KB
  float* Lpart = (float*)(ws + (40ull << 20) + (512ull << 10));  // 384 KB
  int* lo = (int*)(ws + (41ull << 20));                          // 8 KB
  int* hi = (int*)(ws + (41ull << 20) + 8192);                   // 8 KB
  // Opart reuses the dead Kb..Wvb staging region: [26 MiB, 38 MiB) = exactly
  // 3*16*2048*64*2 B = 12 MiB.  proj (reader of Kb/Vb/Wk/Wv) completes before
  // attn (writer of Opart) in stream order.
  unsigned short* Opart = (unsigned short*)(ws + (26ull << 20));

  convert_kernel<<<7312, 256, 0, stream>>>(K, V, Wk, Wv, Wc, rel, Kb, Vb, Wkb, Wvb,
                                           Wcb, relb);
  seg_prep_kernel<<<8, 256, 0, stream>>>(seg, lo, hi);
  qp_kernel<<<128, 256, 0, stream>>>(Q, Qp);
  qe_gemm_kernel<<<dim3(16, 16), 256, 0, stream>>>(Qp, relb, qe);
  proj_kernel<<<512, 256, 0, stream>>>(Kb, Wkb, Wvb, Vb, Kp, Vp);
  attn_kernel<<<dim3(32, 16, 3), dim3(256), 0, stream>>>(Qp, Kp, Vp, qe, lo, hi,
                                                         Opart, Lpart);
  merge_kernel<<<2048, 256, 0, stream>>>(Opart, Lpart, heads);
  outproj_kernel<<<256, 256, 0, stream>>>(heads, Wcb, out);
}

// Round 8
// 203.151 us; speedup vs baseline: 1.0451x; 1.0451x over previous
//
#include <hip/hip_runtime.h>
#include <stdint.h>

// ---------------------------------------------------------------------------
// MultiHeadAttention_19224273617233  (B=1, S1=S2=2048, D=1024, H=16, D_K=64,
// RADIUS=64, SEGMENTED, dense softmax over all 2048 keys)
//
// R8 pipeline (all bf16 MFMA internally; f32 in/out; tol = 2% of absmax):
//   1. prep    : convert K,V,Wk,Wv,Wc,rel -> bf16  +  seg intervals  +  Qp
//   2. qe_proj : fused: qe[h][i][l] GEMM (256 blk) + Kp/Vp proj GEMM (512 blk)
//   3. attn    : 512 thr / 128 q-rows / j-halves; grid 16x16x2 = 2 blk/CU
//                (4 waves/SIMD); no-max softmax (exp2), all-ones row-sum MFMA;
//                unnormalized O/l partials
//   4. merge   : heads = (sum_jh O_jh) / (sum_jh l_jh)  (bf16)
//   5. outproj : out = heads @ Wc^T (f32), 128x64 dbuf
// ---------------------------------------------------------------------------

typedef __attribute__((ext_vector_type(4))) float f32x4;
typedef __attribute__((ext_vector_type(8))) short s16x8;
typedef __attribute__((ext_vector_type(4))) unsigned short u16x4;
typedef __attribute__((ext_vector_type(2))) unsigned short u16x2;

#define MFMA16(a, b, c) __builtin_amdgcn_mfma_f32_16x16x32_bf16((a), (b), (c), 0, 0, 0)

// Q pre-scale: 1/sqrt(D_K)=1/8 folded with log2(e) so softmax uses raw v_exp_f32
#define QSCALE 0.1803368801111204f

__device__ __forceinline__ unsigned short f2bf(float f) {
  unsigned int u = __builtin_bit_cast(unsigned int, f);
  u += 0x7fffu + ((u >> 16) & 1u);  // round-to-nearest-even
  return (unsigned short)(u >> 16);
}
__device__ __forceinline__ float bf2f(unsigned short b) {
  unsigned int u = ((unsigned int)b) << 16;
  return __builtin_bit_cast(float, u);
}

// async 16B/lane global->LDS DMA; LDS dest is wave-uniform base + lane*16
__device__ __forceinline__ void async_copy16(const void* g, void* l) {
  __builtin_amdgcn_global_load_lds(
      (const __attribute__((address_space(1))) unsigned int*)g,
      (__attribute__((address_space(3))) unsigned int*)l, 16, 0, 0);
}

// ---------------------------------------------------------------------------
// prep: fused convert (blocks [0,7312)) + qp (blocks [7312,7440)) +
//       seg_prep (blocks [7440,7448)).  All independent work.
// ---------------------------------------------------------------------------
__global__ __launch_bounds__(256) void prep_kernel(
    const float* __restrict__ Q, const float* __restrict__ K,
    const float* __restrict__ V, const int* __restrict__ seg,
    const float* __restrict__ Wk, const float* __restrict__ Wv,
    const float* __restrict__ Wc, const float* __restrict__ rel,
    unsigned short* __restrict__ Kb, unsigned short* __restrict__ Vb,
    unsigned short* __restrict__ Wkb, unsigned short* __restrict__ Wvb,
    unsigned short* __restrict__ Wcb, unsigned short* __restrict__ relb,
    unsigned short* __restrict__ Qp, int* __restrict__ lo, int* __restrict__ hi) {
  __shared__ __align__(16) unsigned short QL[16][1032];
  const int tid = threadIdx.x;
  const int bx = blockIdx.x;

  if (bx < 7312) {  // ---- convert ----
    size_t v = (size_t)bx * 256 + tid;  // vec4 index
    const size_t M4 = 1u << 18;         // 1M elems in vec4 units
    if (v >= 7 * M4) {
      size_t rv = v - 7 * M4;  // relb: 16*144*16 = 36864 vec4 chunks
      if (rv >= 36864) return;
      int hh = (int)(rv / (144 * 16));
      int rem = (int)(rv % (144 * 16));
      int l = rem >> 4, dch = rem & 15;
      u16x4 p = {0, 0, 0, 0};
      if (l < 130) {
        f32x4 x = ((const f32x4*)rel)[((size_t)hh * 130 + l) * 16 + dch];
        p = (u16x4){f2bf(x[0]), f2bf(x[1]), f2bf(x[2]), f2bf(x[3])};
      }
      ((u16x4*)relb)[rv] = p;
      return;
    }
    const float* src;
    unsigned short* dst;
    size_t off;
    if (v < 2 * M4) { src = K; dst = Kb; off = v; }
    else if (v < 4 * M4) { src = V; dst = Vb; off = v - 2 * M4; }
    else if (v < 5 * M4) { src = Wk; dst = Wkb; off = v - 4 * M4; }
    else if (v < 6 * M4) { src = Wv; dst = Wvb; off = v - 5 * M4; }
    else { src = Wc; dst = Wcb; off = v - 6 * M4; }
    f32x4 x = ((const f32x4*)src)[off];
    u16x4 p = {f2bf(x[0]), f2bf(x[1]), f2bf(x[2]), f2bf(x[3])};
    ((u16x4*)dst)[off] = p;
  } else if (bx < 7440) {  // ---- qp ----
    const int i0 = (bx - 7312) * 16;
#pragma unroll
    for (int ii = 0; ii < 16; ++ii) {
      int lin = tid + 256 * ii;
      int row = lin >> 8, ch = lin & 255;
      f32x4 v = *(const f32x4*)(Q + (size_t)(i0 + row) * 1024 + ch * 4);
      u16x4 pk = {f2bf(v[0]), f2bf(v[1]), f2bf(v[2]), f2bf(v[3])};
      *(u16x4*)&QL[row][ch * 4] = pk;
    }
    __syncthreads();
    const int i = tid & 15, hh = tid >> 4;
#pragma unroll
    for (int d4 = 0; d4 < 16; ++d4) {
      u16x4 pk;
#pragma unroll
      for (int e = 0; e < 4; ++e)
        pk[e] = f2bf(bf2f(QL[i][(d4 * 4 + e) * 16 + hh]) * QSCALE);
      *(u16x4*)(Qp + ((size_t)hh * 2048 + i0 + i) * 64 + d4 * 4) = pk;
    }
  } else {  // ---- seg_prep ----
    const int i = (bx - 7440) * 256 + tid;  // 2048
    const bool is64 = (seg[2047] == 0);
    auto rd = [&](int k) { return is64 ? seg[2 * k] : seg[k]; };
    const int s = rd(i);
    int a = 0, b = i;
    while (a < b) { int m = (a + b) >> 1; if (rd(m) < s) a = m + 1; else b = m; }
    lo[i] = a;
    int c = i, d = 2048;
    while (c < d) { int m = (c + d) >> 1; if (rd(m) <= s) c = m + 1; else d = m; }
    hi[i] = c - 1;
  }
}

// ---------------------------------------------------------------------------
// GEMM core: 128x64 tile, BK=64, double-buffered async staging.
// ---------------------------------------------------------------------------
__device__ __forceinline__ void gemm_core_128x64_db(
    const unsigned short* __restrict__ A, const unsigned short* __restrict__ B,
    int bm, int bn, int K, unsigned short* As, unsigned short* Bs,
    f32x4 (&acc)[4][2]) {
  const int tid = threadIdx.x;
  const int lane = tid & 63, w = tid >> 6;
  const int col = lane & 15, quad = lane >> 4;
  const int wm = (w >> 1) * 64, wn = (w & 1) * 32;
  const int lr = lane >> 3, lc = lane & 7;  // 8 rows x 8 chunks per issue

  auto stage = [&](int buf, int kt) {
#pragma unroll
    for (int t = 0; t < 4; ++t) {  // A: 128 rows
      int r = (w + t * 4) * 8 + lr;
      async_copy16(A + (size_t)(bm + r) * K + kt * 64 + (size_t)(lc ^ (r & 7)) * 8,
                   As + buf * 8192 + (w + t * 4) * 512);
    }
#pragma unroll
    for (int t = 0; t < 2; ++t) {  // B: 64 rows
      int r = (w + t * 4) * 8 + lr;
      async_copy16(B + (size_t)(bn + r) * K + kt * 64 + (size_t)(lc ^ (r & 7)) * 8,
                   Bs + buf * 4096 + (w + t * 4) * 512);
    }
  };

  const int nk = K >> 6;
  stage(0, 0);
  for (int kt = 0; kt < nk; ++kt) {
    __syncthreads();
    if (kt + 1 < nk) stage((kt + 1) & 1, kt + 1);
    const unsigned short* Ab = As + (kt & 1) * 8192;
    const unsigned short* Bb = Bs + (kt & 1) * 4096;

    s16x8 af[4][2], bfr[2][2];
#pragma unroll
    for (int ms = 0; ms < 4; ++ms) {
      int r = wm + ms * 16 + col;
#pragma unroll
      for (int kk = 0; kk < 2; ++kk)
        af[ms][kk] = *(const s16x8*)&Ab[r * 64 + ((kk * 4 + quad) ^ (r & 7)) * 8];
    }
#pragma unroll
    for (int ns = 0; ns < 2; ++ns) {
      int r = wn + ns * 16 + col;
#pragma unroll
      for (int kk = 0; kk < 2; ++kk)
        bfr[ns][kk] = *(const s16x8*)&Bb[r * 64 + ((kk * 4 + quad) ^ (r & 7)) * 8];
    }
#pragma unroll
    for (int kk = 0; kk < 2; ++kk)
#pragma unroll
      for (int ms = 0; ms < 4; ++ms)
#pragma unroll
        for (int ns = 0; ns < 2; ++ns)
          acc[ms][ns] = MFMA16(af[ms][kk], bfr[ns][kk], acc[ms][ns]);
  }
}

// ---------------------------------------------------------------------------
// qe_proj fused:
//   blocks [0,256)   : qe[h][i0..i0+128][0..144) = Qp-tile @ relb[h]^T
//   blocks [256,512) : Kp[h][j][d] = K@Wk^T   (128x64 tiles)
//   blocks [512,768) : Vp[h][d][j] = (V@Wv^T)^T
// Shared 48 KB LDS (union of both branches); 768 blocks = 3 blocks/CU.
// ---------------------------------------------------------------------------
__global__ __launch_bounds__(256, 3) void qe_proj_kernel(
    const unsigned short* __restrict__ Qp, const unsigned short* __restrict__ relb,
    const unsigned short* __restrict__ Kb, const unsigned short* __restrict__ Wkb,
    const unsigned short* __restrict__ Wvb, const unsigned short* __restrict__ Vb,
    unsigned short* __restrict__ qe, unsigned short* __restrict__ Kp,
    unsigned short* __restrict__ Vp) {
  __shared__ __align__(16) unsigned short smem[24576];  // 48 KB

  const int tid = threadIdx.x;
  const int lane = tid & 63, w = tid >> 6;
  const int col = lane & 15, quad = lane >> 4;
  const int bx = blockIdx.x;
  const int lr = lane >> 3, lc = lane & 7;

  if (bx < 256) {  // ---- qe_gemm ----
    unsigned short* As = smem;           // 128*64
    unsigned short* Bs = smem + 8192;    // 144*72
    const int h = bx >> 4;
    const int i0 = (bx & 15) * 128;

#pragma unroll
    for (int t = 0; t < 4; ++t) {
      int r = (w + t * 4) * 8 + lr;
      async_copy16(Qp + ((size_t)(h * 2048 + i0 + r)) * 64 + (size_t)(lc ^ (r & 7)) * 8,
                   As + (w + t * 4) * 512);
    }
    for (int c = tid; c < 1152; c += 256) {
      int row = c >> 3, ch = c & 7;
      *(f32x4*)&Bs[row * 72 + ch * 8] =
          *(const f32x4*)(relb + ((size_t)(h * 144 + row)) * 64 + ch * 8);
    }
    __syncthreads();

    s16x8 af[2][2];
#pragma unroll
    for (int ms = 0; ms < 2; ++ms) {
      int r = w * 32 + ms * 16 + col;
#pragma unroll
      for (int kk = 0; kk < 2; ++kk)
        af[ms][kk] = *(const s16x8*)&As[r * 64 + ((kk * 4 + quad) ^ (r & 7)) * 8];
    }

    f32x4 acc[2][9];
#pragma unroll
    for (int ms = 0; ms < 2; ++ms)
#pragma unroll
      for (int ns = 0; ns < 9; ++ns) acc[ms][ns] = (f32x4){0.f, 0.f, 0.f, 0.f};

#pragma unroll
    for (int ns = 0; ns < 9; ++ns) {
      s16x8 b0 = *(const s16x8*)&Bs[(ns * 16 + col) * 72 + quad * 8];
      s16x8 b1 = *(const s16x8*)&Bs[(ns * 16 + col) * 72 + 32 + quad * 8];
#pragma unroll
      for (int ms = 0; ms < 2; ++ms) {
        acc[ms][ns] = MFMA16(af[ms][0], b0, acc[ms][ns]);
        acc[ms][ns] = MFMA16(af[ms][1], b1, acc[ms][ns]);
      }
    }

#pragma unroll
    for (int ms = 0; ms < 2; ++ms)
#pragma unroll
      for (int ns = 0; ns < 9; ++ns)
#pragma unroll
        for (int r = 0; r < 4; ++r) {
          int m = i0 + w * 32 + ms * 16 + quad * 4 + r;
          qe[((size_t)h * 2048 + m) * 144 + ns * 16 + col] = f2bf(acc[ms][ns][r]);
        }
    return;
  }

  // ---- proj ----
  unsigned short* As = smem;            // 2*128*64
  unsigned short* Bs = smem + 16384;    // 2*64*64
  const bool modeK = bx < 512;
  const unsigned short *A, *B;
  int bm, bn;
  if (modeK) {
    int b = bx - 256;
    A = Kb; B = Wkb;                    // M=2048 (j), N=1024 (o)
    bm = (b >> 4) * 128; bn = (b & 15) * 64;
  } else {
    int b = bx - 512;
    A = Wvb; B = Vb;                    // M=1024 (o), N=2048 (j)
    bm = (b >> 5) * 128; bn = (b & 31) * 64;
  }

  f32x4 acc[4][2];
#pragma unroll
  for (int a = 0; a < 4; ++a)
#pragma unroll
    for (int b2 = 0; b2 < 2; ++b2) acc[a][b2] = (f32x4){0.f, 0.f, 0.f, 0.f};

  gemm_core_128x64_db(A, B, bm, bn, 1024, As, Bs, acc);

  const int wm = (w >> 1) * 64, wn = (w & 1) * 32;
  if (modeK) {
    const int dbase = (bn + wn) >> 4;
#pragma unroll
    for (int ms = 0; ms < 4; ++ms)
#pragma unroll
      for (int r = 0; r < 4; ++r) {
        int m = bm + wm + ms * 16 + quad * 4 + r;
        u16x2 pk = {f2bf(acc[ms][0][r]), f2bf(acc[ms][1][r])};
        *(u16x2*)(Kp + ((size_t)col * 2048 + m) * 64 + dbase) = pk;
      }
  } else {
#pragma unroll
    for (int ms = 0; ms < 4; ++ms)
#pragma unroll
      for (int r = 0; r < 4; ++r) {
        int m = bm + wm + ms * 16 + quad * 4 + r;
        int hh = m & 15, dd = m >> 4;
#pragma unroll
        for (int ns = 0; ns < 2; ++ns) {
          int j = bn + wn + ns * 16 + col;
          Vp[((size_t)hh * 64 + dd) * 2048 + j] = f2bf(acc[ms][ns][r]);
        }
      }
  }
}

// ---------------------------------------------------------------------------
// outproj: out[i][n] = sum_o heads[i][o] * Wc[n][o]   (f32 out)
// ---------------------------------------------------------------------------
__global__ __launch_bounds__(256, 2) void outproj_kernel(
    const unsigned short* __restrict__ Hb, const unsigned short* __restrict__ Wcb,
    float* __restrict__ out) {
  __shared__ __align__(16) unsigned short As[2 * 128 * 64];
  __shared__ __align__(16) unsigned short Bs[2 * 64 * 64];

  const int bx = blockIdx.x;
  const int bm = (bx >> 4) * 128, bn = (bx & 15) * 64;

  f32x4 acc[4][2];
#pragma unroll
  for (int a = 0; a < 4; ++a)
#pragma unroll
    for (int b2 = 0; b2 < 2; ++b2) acc[a][b2] = (f32x4){0.f, 0.f, 0.f, 0.f};

  gemm_core_128x64_db(Hb, Wcb, bm, bn, 1024, As, Bs, acc);

  const int lane = threadIdx.x & 63, w = threadIdx.x >> 6;
  const int col = lane & 15, quad = lane >> 4;
  const int wm = (w >> 1) * 64, wn = (w & 1) * 32;
#pragma unroll
  for (int ms = 0; ms < 4; ++ms)
#pragma unroll
    for (int ns = 0; ns < 2; ++ns)
#pragma unroll
      for (int r = 0; r < 4; ++r) {
        int m = bm + wm + ms * 16 + quad * 4 + r;
        int n = bn + wn + ns * 16 + col;
        out[(size_t)m * 1024 + n] = acc[ms][ns][r];
      }
}

// ---------------------------------------------------------------------------
// attn: 512 threads (8 waves), 128 q-rows/block, j-halves.
// grid (16 i-tiles, 16 heads, 2 j-halves) = 512 blocks = 2/CU, 4 waves/SIMD.
// Inner loop identical to the R7-verified kernel; 8 waves share each 64x64
// K/V tile (per-wave staging halves, 2x MFMA per barrier).
// Emits unnormalized partials Opart[jh][h][i][d] (bf16), Lpart[jh][h][i] (f32).
// ---------------------------------------------------------------------------
__global__ __launch_bounds__(512, 4) void attn_kernel(
    const unsigned short* __restrict__ Qp, const unsigned short* __restrict__ Kp,
    const unsigned short* __restrict__ Vp, const unsigned short* __restrict__ qe,
    const int* __restrict__ lo, const int* __restrict__ hi,
    unsigned short* __restrict__ Opart, float* __restrict__ Lpart) {
  __shared__ __align__(16) unsigned short Kt[64 * 64];   // [j][d], swizzled
  __shared__ __align__(16) unsigned short Vt[64 * 64];   // [d][j], swizzled
  __shared__ __align__(16) unsigned short QE[128][144];  // [i_local][l]
  __shared__ __align__(16) unsigned short Pst[8][16][72];
  __shared__ int loL[128], hiL[128];

  const int tid = threadIdx.x;
  const int lane = tid & 63;
  const int w = tid >> 6;                    // 0..7
  const int col = lane & 15;
  const int quad = lane >> 4;
  const int h = blockIdx.y;
  const int bi = blockIdx.x;
  const int i0 = bi * 128;
  const int jh = blockIdx.z;                 // j-half
  const int jt_beg = jh * 16;
  const int lr = lane >> 3, lc = lane & 7;

  if (tid < 128) { loL[tid] = lo[i0 + tid]; hiL[tid] = hi[i0 + tid]; }
#pragma unroll
  for (int ii = 0; ii < 5; ++ii) {
    int lin = tid + 512 * ii;  // 128 rows x 18 chunks = 2304
    if (lin < 2304) {
      int row = lin / 18, ch = lin % 18;
      *(f32x4*)&QE[row][ch * 8] =
          *(const f32x4*)(qe + ((size_t)(h * 2048 + i0 + row)) * 144 + ch * 8);
    }
  }
  __syncthreads();

  // per-row (4 rows per lane) constants
  int il[4], lo_r[4];
  unsigned span[4];
  float c0[4], c128[4], c129[4];
#pragma unroll
  for (int r = 0; r < 4; ++r) {
    il[r] = w * 16 + quad * 4 + r;
    lo_r[r] = loL[il[r]];
    span[r] = (unsigned)(hiL[il[r]] - lo_r[r]);
    c0[r] = bf2f(QE[il[r]][0]);
    c128[r] = bf2f(QE[il[r]][128]);
    c129[r] = bf2f(QE[il[r]][129]);
  }

  const int iw = i0 + w * 16;
  s16x8 aq0 = *(const s16x8*)(Qp + ((size_t)(h * 2048 + iw + col)) * 64 + quad * 8);
  s16x8 aq1 = *(const s16x8*)(Qp + ((size_t)(h * 2048 + iw + col)) * 64 + 32 + quad * 8);

  s16x8 ones;
#pragma unroll
  for (int e = 0; e < 8; ++e) ones[e] = (short)0x3F80;  // bf16 1.0

  f32x4 o[4], o4;
#pragma unroll
  for (int t = 0; t < 4; ++t) o[t] = (f32x4){0.f, 0.f, 0.f, 0.f};
  o4 = (f32x4){0.f, 0.f, 0.f, 0.f};

  for (int jtl = 0; jtl < 16; ++jtl) {
    const int jt = jt_beg + jtl;
    const int j0 = jt * 64;
    __syncthreads();  // previous tile fully consumed
    {
      // 8 waves x 8 rows: each wave stages one K-slice and one V-slice
      int r = w * 8 + lr;
      async_copy16(Kp + ((size_t)(h * 2048 + j0 + r)) * 64 + (size_t)(lc ^ (r & 7)) * 8,
                   Kt + w * 512);
      async_copy16(Vp + ((size_t)(h * 64 + r)) * 2048 + j0 + (size_t)(lc ^ (r & 7)) * 8,
                   Vt + w * 512);
    }
    __syncthreads();  // DMA drained

    // S = (Q*QSCALE) K^T  (16 x 64 per wave), log2-domain
    f32x4 s[4];
#pragma unroll
    for (int ns = 0; ns < 4; ++ns) {
      int r = ns * 16 + col, sw = r & 7;
      s16x8 bk0 = *(const s16x8*)&Kt[r * 64 + (quad ^ sw) * 8];
      s16x8 bk1 = *(const s16x8*)&Kt[r * 64 + ((quad + 4) ^ sw) * 8];
      f32x4 z = (f32x4){0.f, 0.f, 0.f, 0.f};
      z = MFMA16(aq0, bk0, z);
      z = MFMA16(aq1, bk1, z);
      s[ns] = z;
    }

    // + bias (qe carries the same QSCALE factor), then P = exp2(s)
    // near-diagonal band for a 128-row block: jt in [2*bi-1, 2*bi+2]
    const int dt = jt - 2 * bi;
    if (dt < -1 || dt > 2) {
      const bool right = dt > 2;  // wave-uniform
#pragma unroll
      for (int ns = 0; ns < 4; ++ns) {
        int j = j0 + ns * 16 + col;
#pragma unroll
        for (int r = 0; r < 4; ++r) {
          float cin = right ? c128[r] : c0[r];
          bool same = (unsigned)(j - lo_r[r]) <= span[r];
          s[ns][r] += same ? cin : c129[r];
        }
      }
    } else {
#pragma unroll
      for (int ns = 0; ns < 4; ++ns) {
        int j = j0 + ns * 16 + col;
#pragma unroll
        for (int r = 0; r < 4; ++r) {
          int rel = j - (i0 + il[r]);
          int rc = rel < -64 ? -64 : (rel > 64 ? 64 : rel);
          bool same = (unsigned)(j - lo_r[r]) <= span[r];
          int idx = same ? (rc + 64) : 129;
          s[ns][r] += bf2f(QE[il[r]][idx]);
        }
      }
    }
#pragma unroll
    for (int ns = 0; ns < 4; ++ns)
#pragma unroll
      for (int r = 0; r < 4; ++r)
        s[ns][r] = __builtin_amdgcn_exp2f(fminf(s[ns][r], 60.f));

    // P: C-layout -> A-layout via per-wave LDS region (wave-private)
#pragma unroll
    for (int ns = 0; ns < 4; ++ns)
#pragma unroll
      for (int r = 0; r < 4; ++r)
        Pst[w][quad * 4 + r][ns * 16 + col] = f2bf(s[ns][r]);

    s16x8 ap0 = *(const s16x8*)&Pst[w][col][quad * 8];
    s16x8 ap1 = *(const s16x8*)&Pst[w][col][32 + quad * 8];
#pragma unroll
    for (int t = 0; t < 4; ++t) {
      int r = t * 16 + col, sw = r & 7;
      s16x8 bv0 = *(const s16x8*)&Vt[r * 64 + (quad ^ sw) * 8];
      s16x8 bv1 = *(const s16x8*)&Vt[r * 64 + ((quad + 4) ^ sw) * 8];
      o[t] = MFMA16(ap0, bv0, o[t]);
      o[t] = MFMA16(ap1, bv1, o[t]);
    }
    o4 = MFMA16(ap0, ones, o4);  // row sums: every column gets sum_j P[i][j]
    o4 = MFMA16(ap1, ones, o4);
  }

  // emit unnormalized partials
#pragma unroll
  for (int t = 0; t < 4; ++t)
#pragma unroll
    for (int r = 0; r < 4; ++r) {
      int i = i0 + w * 16 + quad * 4 + r;
      int d = t * 16 + col;
      Opart[(((size_t)jh * 16 + h) * 2048 + i) * 64 + d] = f2bf(o[t][r]);
    }
  if (col == 0) {
#pragma unroll
    for (int r = 0; r < 4; ++r) {
      int i = i0 + w * 16 + quad * 4 + r;
      Lpart[((size_t)jh * 16 + h) * 2048 + i] = o4[r];
    }
  }
}

// ---------------------------------------------------------------------------
// merge: heads[i][d*16+h] = (sum_jh Opart) / (sum_jh Lpart)
// ---------------------------------------------------------------------------
__global__ __launch_bounds__(256) void merge_kernel(
    const unsigned short* __restrict__ Opart, const float* __restrict__ Lpart,
    unsigned short* __restrict__ heads) {
  const int idx = blockIdx.x * 256 + threadIdx.x;
  const int d4 = idx & 15;
  const int i = (idx >> 4) & 2047;
  const int h = idx >> 15;

  float o0 = 0.f, o1 = 0.f, o2 = 0.f, o3 = 0.f, l = 0.f;
#pragma unroll
  for (int jh = 0; jh < 2; ++jh) {
    size_t base = (((size_t)jh * 16 + h) * 2048 + i) * 64 + d4 * 4;
    u16x4 p = *(const u16x4*)(Opart + base);
    o0 += bf2f(p[0]); o1 += bf2f(p[1]); o2 += bf2f(p[2]); o3 += bf2f(p[3]);
    l += Lpart[((size_t)jh * 16 + h) * 2048 + i];
  }
  const float inv = 1.f / l;
  unsigned short* dst = heads + (size_t)i * 1024 + (size_t)d4 * 64 + h;
  dst[0] = f2bf(o0 * inv);
  dst[16] = f2bf(o1 * inv);
  dst[32] = f2bf(o2 * inv);
  dst[48] = f2bf(o3 * inv);
}

// ---------------------------------------------------------------------------
extern "C" void kernel_launch(void* const* d_in, const int* in_sizes, int n_in,
                              void* d_out, int out_size, void* d_ws, size_t ws_size,
                              hipStream_t stream) {
  const float* Q = (const float*)d_in[0];
  const float* K = (const float*)d_in[1];
  const float* V = (const float*)d_in[2];
  const int* seg = (const int*)d_in[3];
  // d_in[4] = padding_mask: all-false, unused (HARD_MASKING=False)
  const float* Wk = (const float*)d_in[5];
  const float* Wv = (const float*)d_in[6];
  const float* Wc = (const float*)d_in[7];
  const float* rel = (const float*)d_in[8];
  float* out = (float*)d_out;

  char* ws = (char*)d_ws;
  unsigned short* Kp = (unsigned short*)(ws);                    // [16][2048][64] 4 MB
  unsigned short* Vp = (unsigned short*)(ws + (4ull << 20));     // [16][64][2048] 4 MB
  unsigned short* Qp = (unsigned short*)(ws + (8ull << 20));     // [16][2048][64] 4 MB
  unsigned short* heads = (unsigned short*)(ws + (12ull << 20)); // [2048][1024] 4 MB
  unsigned short* qe = (unsigned short*)(ws + (16ull << 20));    // [16][2048][144] 9.4 MB
  unsigned short* Kb = (unsigned short*)(ws + (26ull << 20));    // 4 MB (dead after qe_proj)
  unsigned short* Vb = (unsigned short*)(ws + (30ull << 20));    // 4 MB (dead after qe_proj)
  unsigned short* Wkb = (unsigned short*)(ws + (34ull << 20));   // 2 MB (dead after qe_proj)
  unsigned short* Wvb = (unsigned short*)(ws + (36ull << 20));   // 2 MB (dead after qe_proj)
  unsigned short* Wcb = (unsigned short*)(ws + (38ull << 20));   // 2 MB
  unsigned short* relb = (unsigned short*)(ws + (40ull << 20));  // 288 KB
  float* Lpart = (float*)(ws + (40ull << 20) + (512ull << 10));  // 256 KB
  int* lo = (int*)(ws + (41ull << 20));                          // 8 KB
  int* hi = (int*)(ws + (41ull << 20) + 8192);                   // 8 KB
  // Opart reuses the dead Kb..Wvb staging region: 2*16*2048*64*2 B = 8 MiB.
  // qe_proj (reader of Kb/Vb/Wkb/Wvb) completes before attn in stream order.
  unsigned short* Opart = (unsigned short*)(ws + (26ull << 20));

  prep_kernel<<<7448, 256, 0, stream>>>(Q, K, V, seg, Wk, Wv, Wc, rel, Kb, Vb, Wkb,
                                        Wvb, Wcb, relb, Qp, lo, hi);
  qe_proj_kernel<<<768, 256, 0, stream>>>(Qp, relb, Kb, Wkb, Wvb, Vb, qe, Kp, Vp);
  attn_kernel<<<dim3(16, 16, 2), dim3(512), 0, stream>>>(Qp, Kp, Vp, qe, lo, hi,
                                                         Opart, Lpart);
  merge_kernel<<<2048, 256, 0, stream>>>(Opart, Lpart, heads);
  outproj_kernel<<<256, 256, 0, stream>>>(heads, Wcb, out);
}